// Round 1
// baseline (1194.395 us; speedup 1.0000x reference)
//
#include <hip/hip_runtime.h>
#include <math.h>

#define NPTS 262144
#define TTAB 524288
#define TMASK (TTAB - 1)
#define PR1 2654435761u
#define PR2 805459861u

typedef __attribute__((ext_vector_type(4))) float f32x4;
typedef __attribute__((ext_vector_type(8))) short bf16x8;

struct ResArr { float r[16]; };

__device__ __forceinline__ float bf2f(unsigned short u) {
  union { unsigned int i; float f; } v; v.i = ((unsigned int)u) << 16; return v.f;
}
__device__ __forceinline__ unsigned short f2bf(float f) {
  union { float f; unsigned int i; } v; v.f = f;
  unsigned int r = v.i + 0x7FFFu + ((v.i >> 16) & 1u);
  return (unsigned short)(r >> 16);
}

// ---------------------------------------------------------------------------
// Kernel A1: hash-grid encode. One thread per (table, point).
// Writes bf16 feature rows to ws (fs/cs/ss) and plane_feat (fp32) to d_out.
// ---------------------------------------------------------------------------
__global__ __launch_bounds__(256) void hash_kernel(
    const float* __restrict__ p, const float* __restrict__ bound,
    const float* __restrict__ t_sdf, const float* __restrict__ t_color,
    const float* __restrict__ t_sem,
    unsigned short* __restrict__ fs, unsigned short* __restrict__ cs,
    unsigned short* __restrict__ ss, float* __restrict__ out, ResArr res)
{
  int bid = blockIdx.x;
  int tb = bid >> 10;                       // 0: sdf, 1: color, 2: sem
  int n = ((bid & 1023) << 8) | threadIdx.x;
  const float* __restrict__ tab = (tb == 0) ? t_sdf : (tb == 1) ? t_color : t_sem;
  unsigned short* fout = (tb == 0) ? fs : (tb == 1) ? cs : ss;
  int pfoff = (tb == 0) ? 16 : (tb == 1) ? 0 : 32;  // plane_feat = [c,f,s]

  float px = p[n * 3 + 0], py = p[n * 3 + 1], pz = p[n * 3 + 2];
  float x = (px - bound[0]) / (bound[1] - bound[0]);
  float y = (py - bound[2]) / (bound[3] - bound[2]);
  float z = (pz - bound[4]) / (bound[5] - bound[4]);

  float feat[32];
#pragma unroll
  for (int l = 0; l < 16; ++l) {
    float r = res.r[l];
    float sx = x * r, sy = y * r, sz = z * r;
    float fx = floorf(sx), fy = floorf(sy), fz = floorf(sz);
    float dx = sx - fx, dy = sy - fy, dz = sz - fz;
    unsigned int cx = (unsigned int)fx, cy = (unsigned int)fy, cz = (unsigned int)fz;
    unsigned int hx[2] = { cx, cx + 1u };
    unsigned int hy[2] = { cy * PR1, (cy + 1u) * PR1 };
    unsigned int hz[2] = { cz * PR2, (cz + 1u) * PR2 };
    float wx[2] = { 1.f - dx, dx }, wy[2] = { 1.f - dy, dy }, wz[2] = { 1.f - dz, dz };
    const float* tl = tab + (size_t)l * (TTAB * 2);
    float a0 = 0.f, a1 = 0.f;
#pragma unroll
    for (int i = 0; i < 2; ++i)
#pragma unroll
      for (int j = 0; j < 2; ++j)
#pragma unroll
        for (int k = 0; k < 2; ++k) {
          unsigned int idx = (hx[i] ^ hy[j] ^ hz[k]) & TMASK;
          float2 f2 = *(const float2*)(tl + (size_t)idx * 2);
          float w = wx[i] * wy[j] * wz[k];
          a0 += f2.x * w;
          a1 += f2.y * w;
        }
    feat[2 * l] = a0;
    feat[2 * l + 1] = a1;
  }

  // bf16 feature row -> ws (vectorized 4x16B)
  alignas(16) unsigned short tmp[32];
#pragma unroll
  for (int i = 0; i < 32; ++i) tmp[i] = f2bf(feat[i]);
  uint4* dst = (uint4*)(fout + (size_t)n * 32);
  const uint4* sv = (const uint4*)tmp;
  dst[0] = sv[0]; dst[1] = sv[1]; dst[2] = sv[2]; dst[3] = sv[3];

  // plane_feat (levels 8..15 = elements 16..31), fp32 exact
  float* pf = out + (size_t)NPTS * 29 + (size_t)n * 48 + pfoff;
#pragma unroll
  for (int i = 0; i < 16; i += 4)
    *(float4*)(pf + i) = make_float4(feat[16 + i], feat[17 + i], feat[18 + i], feat[19 + i]);
}

// ---------------------------------------------------------------------------
// Kernel A2: small MLPs (sdf chain + rgb). One thread per point.
// Weights read with wave-uniform indices -> compiler scalarizes to s_load.
// ---------------------------------------------------------------------------
__global__ __launch_bounds__(256) void mlp_small_kernel(
    const unsigned short* __restrict__ fs, const unsigned short* __restrict__ cs,
    const unsigned short* __restrict__ ss,
    const float* __restrict__ fw0, const float* __restrict__ fb0,
    const float* __restrict__ fw1, const float* __restrict__ fb1,
    const float* __restrict__ fw2, const float* __restrict__ fb2,
    const float* __restrict__ fw3, const float* __restrict__ fb3,
    const float* __restrict__ ow, const float* __restrict__ ob,
    const float* __restrict__ rw0, const float* __restrict__ rb0,
    const float* __restrict__ rw1, const float* __restrict__ rb1,
    float* __restrict__ out)
{
  int n = blockIdx.x * 256 + threadIdx.x;
  alignas(16) unsigned short uf[32], uc[32], us[32];
  {
    const uint4* a4 = (const uint4*)(fs + (size_t)n * 32);
    const uint4* b4 = (const uint4*)(cs + (size_t)n * 32);
    const uint4* c4 = (const uint4*)(ss + (size_t)n * 32);
    uint4* ua = (uint4*)uf; uint4* ub = (uint4*)uc; uint4* uc2 = (uint4*)us;
#pragma unroll
    for (int i = 0; i < 4; ++i) { ua[i] = a4[i]; ub[i] = b4[i]; uc2[i] = c4[i]; }
  }
  float ft[32], cf[32], sf[32];
#pragma unroll
  for (int i = 0; i < 32; ++i) { ft[i] = bf2f(uf[i]); cf[i] = bf2f(uc[i]); sf[i] = bf2f(us[i]); }

  float h[16], g[16];
  for (int o = 0; o < 16; ++o) {
    float a = fb0[o];
    for (int i = 0; i < 32; ++i) a += ft[i] * fw0[o * 32 + i];
    h[o] = fmaxf(a, 0.f);
  }
  for (int o = 0; o < 16; ++o) {
    float a = fb1[o];
    for (int i = 0; i < 16; ++i) a += h[i] * fw1[o * 16 + i];
    g[o] = fmaxf(a, 0.f);
  }
  for (int o = 0; o < 16; ++o) {
    float a = fb2[o];
    for (int i = 0; i < 16; ++i) a += g[i] * fw2[o * 16 + i];
    h[o] = fmaxf(a, 0.f);
  }
  for (int o = 0; o < 16; ++o) {
    float a = fb3[o];
    for (int i = 0; i < 16; ++i) a += h[i] * fw3[o * 16 + i];
    g[o] = fmaxf(a, 0.f);
  }
  float so[17];
  for (int o = 0; o < 17; ++o) {
    float a = ob[o];
    for (int i = 0; i < 16; ++i) a += g[i] * ow[o * 16 + i];
    so[o] = a;
  }
  float sdf = tanhf(so[0]);
  float rin[80];
#pragma unroll
  for (int i = 0; i < 16; ++i) rin[i] = so[i + 1];
#pragma unroll
  for (int i = 0; i < 32; ++i) rin[16 + i] = cf[i];
#pragma unroll
  for (int i = 0; i < 32; ++i) rin[48 + i] = sf[i];
  float hr[16];
  for (int o = 0; o < 16; ++o) {
    float a = rb0[o];
    for (int i = 0; i < 80; ++i) a += rin[i] * rw0[o * 80 + i];
    hr[o] = fmaxf(a, 0.f);
  }
  float* po = out + (size_t)n * 29;
  for (int o = 0; o < 3; ++o) {
    float a = rb1[o];
    for (int i = 0; i < 16; ++i) a += hr[i] * rw1[o * 16 + i];
    po[o] = 1.f / (1.f + expf(-a));
  }
  po[3] = sdf;
}

// ---------------------------------------------------------------------------
// Weight fp32 -> bf16 conversion (semantic MLP weights; wo zero-padded 25->32)
// ---------------------------------------------------------------------------
__global__ __launch_bounds__(256) void cvt_kernel(
    const float* __restrict__ sw0, const float* __restrict__ sw1,
    const float* __restrict__ sw2, const float* __restrict__ swo,
    unsigned short* __restrict__ w0, unsigned short* __restrict__ w1,
    unsigned short* __restrict__ w2, unsigned short* __restrict__ wo)
{
  int t = blockIdx.x * 256 + threadIdx.x;   // grid covers 65536
  if (t < 8192) w0[t] = f2bf(sw0[t]);
  w1[t] = f2bf(sw1[t]);
  w2[t] = f2bf(sw2[t]);
  if (t < 8192) wo[t] = (t < 6400) ? f2bf(swo[t]) : (unsigned short)0;
}

// ---------------------------------------------------------------------------
// Kernel B: semantic MLP 32->256->256->256->25 via bf16 MFMA 16x16x32.
// Block = 256 threads (4 waves), M-tile = 64 points. Activations in LDS
// (stride 264 bf16 -> 2-way bank alias = free). Weights streamed from L2.
// ---------------------------------------------------------------------------
#define LAYER256(Hin, Wp, Bp, Hout)                                                        \
  {                                                                                        \
    _Pragma("unroll") for (int r = 0; r < 4; ++r)                                          \
      _Pragma("unroll") for (int c = 0; c < 4; ++c)                                        \
        acc[r][c] = (f32x4){0.f, 0.f, 0.f, 0.f};                                           \
    _Pragma("unroll") for (int ks = 0; ks < 8; ++ks) {                                     \
      int k0 = ks * 32;                                                                    \
      _Pragma("unroll") for (int r = 0; r < 4; ++r)                                        \
        a[r] = *(const bf16x8*)(Hin + (r * 16 + l16) * 264 + k0 + quad * 8);               \
      _Pragma("unroll") for (int c = 0; c < 4; ++c)                                        \
        b[c] = *(const bf16x8*)(Wp + (size_t)(cw + c * 16 + l16) * 256 + k0 + quad * 8);   \
      _Pragma("unroll") for (int r = 0; r < 4; ++r)                                        \
        _Pragma("unroll") for (int c = 0; c < 4; ++c)                                      \
          acc[r][c] = __builtin_amdgcn_mfma_f32_16x16x32_bf16(a[r], b[c], acc[r][c], 0, 0, 0); \
    }                                                                                      \
    _Pragma("unroll") for (int c = 0; c < 4; ++c) {                                        \
      int col = cw + c * 16 + l16;                                                         \
      float bias = Bp[col];                                                                \
      _Pragma("unroll") for (int r = 0; r < 4; ++r)                                        \
        _Pragma("unroll") for (int g2 = 0; g2 < 4; ++g2) {                                 \
          int row = r * 16 + quad * 4 + g2;                                                \
          Hout[row * 264 + col] = f2bf(fmaxf(acc[r][c][g2] + bias, 0.f));                  \
        }                                                                                  \
    }                                                                                      \
    __syncthreads();                                                                       \
  }

__global__ __launch_bounds__(256) void sem_kernel(
    const unsigned short* __restrict__ ss,
    const unsigned short* __restrict__ w0, const unsigned short* __restrict__ w1,
    const unsigned short* __restrict__ w2, const unsigned short* __restrict__ wo,
    const float* __restrict__ b0, const float* __restrict__ b1,
    const float* __restrict__ b2, const float* __restrict__ bo,
    float* __restrict__ out)
{
  __shared__ alignas(16) unsigned short X[64 * 40];
  __shared__ alignas(16) unsigned short HA[64 * 264];
  __shared__ alignas(16) unsigned short HB[64 * 264];

  int tid = threadIdx.x;
  int n0 = blockIdx.x * 64;
  int lane = tid & 63, wv = tid >> 6;
  int l16 = lane & 15, quad = lane >> 4;
  int cw = wv * 64;

  {
    const uint4* src = (const uint4*)(ss + (size_t)n0 * 32);
    uint4 v = src[tid];
    int row = tid >> 2, cb = tid & 3;
    *(uint4*)(X + row * 40 + cb * 8) = v;
  }
  __syncthreads();

  f32x4 acc[4][4];
  bf16x8 a[4], b[4];

  // ---- layer 0 (K=32): X @ W0^T -> HA ----
#pragma unroll
  for (int r = 0; r < 4; ++r)
#pragma unroll
    for (int c = 0; c < 4; ++c) acc[r][c] = (f32x4){0.f, 0.f, 0.f, 0.f};
#pragma unroll
  for (int r = 0; r < 4; ++r) a[r] = *(const bf16x8*)(X + (r * 16 + l16) * 40 + quad * 8);
#pragma unroll
  for (int c = 0; c < 4; ++c) b[c] = *(const bf16x8*)(w0 + (size_t)(cw + c * 16 + l16) * 32 + quad * 8);
#pragma unroll
  for (int r = 0; r < 4; ++r)
#pragma unroll
    for (int c = 0; c < 4; ++c)
      acc[r][c] = __builtin_amdgcn_mfma_f32_16x16x32_bf16(a[r], b[c], acc[r][c], 0, 0, 0);
#pragma unroll
  for (int c = 0; c < 4; ++c) {
    int col = cw + c * 16 + l16;
    float bias = b0[col];
#pragma unroll
    for (int r = 0; r < 4; ++r)
#pragma unroll
      for (int g2 = 0; g2 < 4; ++g2) {
        int row = r * 16 + quad * 4 + g2;
        HA[row * 264 + col] = f2bf(fmaxf(acc[r][c][g2] + bias, 0.f));
      }
  }
  __syncthreads();

  // ---- layer 1: HA @ W1^T -> HB ----
  LAYER256(HA, w1, b1, HB)
  // ---- layer 2: HB @ W2^T -> HA ----
  LAYER256(HB, w2, b2, HA)

  // ---- output layer (25 cols): HA @ Wo^T -> d_out ----
  f32x4 acc2[2];
  acc2[0] = (f32x4){0.f, 0.f, 0.f, 0.f};
  acc2[1] = (f32x4){0.f, 0.f, 0.f, 0.f};
#pragma unroll
  for (int ks = 0; ks < 8; ++ks) {
    int k0 = ks * 32;
    bf16x8 af = *(const bf16x8*)(HA + (wv * 16 + l16) * 264 + k0 + quad * 8);
#pragma unroll
    for (int c = 0; c < 2; ++c) {
      bf16x8 bf = *(const bf16x8*)(wo + (size_t)(c * 16 + l16) * 256 + k0 + quad * 8);
      acc2[c] = __builtin_amdgcn_mfma_f32_16x16x32_bf16(af, bf, acc2[c], 0, 0, 0);
    }
  }
#pragma unroll
  for (int c = 0; c < 2; ++c) {
    int col = c * 16 + l16;
    if (col < 25) {
      float bias = bo[col];
#pragma unroll
      for (int g2 = 0; g2 < 4; ++g2) {
        int row = wv * 16 + quad * 4 + g2;
        out[(size_t)(n0 + row) * 29 + 4 + col] = acc2[c][g2] + bias;
      }
    }
  }
}

// ---------------------------------------------------------------------------
extern "C" void kernel_launch(void* const* d_in, const int* in_sizes, int n_in,
                              void* d_out, int out_size, void* d_ws, size_t ws_size,
                              hipStream_t stream) {
  const float* p      = (const float*)d_in[0];
  const float* bound  = (const float*)d_in[1];
  const float* t_sdf  = (const float*)d_in[2];
  const float* t_color= (const float*)d_in[3];
  const float* t_sem  = (const float*)d_in[4];
  const float* f_w0   = (const float*)d_in[5];
  const float* f_b0   = (const float*)d_in[6];
  const float* f_w1   = (const float*)d_in[7];
  const float* f_b1   = (const float*)d_in[8];
  const float* f_w2   = (const float*)d_in[9];
  const float* f_b2   = (const float*)d_in[10];
  const float* f_w3   = (const float*)d_in[11];
  const float* f_b3   = (const float*)d_in[12];
  const float* osdf_w = (const float*)d_in[13];
  const float* osdf_b = (const float*)d_in[14];
  const float* orgb_w0= (const float*)d_in[15];
  const float* orgb_b0= (const float*)d_in[16];
  const float* orgb_w1= (const float*)d_in[17];
  const float* orgb_b1= (const float*)d_in[18];
  const float* s_w0   = (const float*)d_in[19];
  const float* s_b0   = (const float*)d_in[20];
  const float* s_w1   = (const float*)d_in[21];
  const float* s_b1   = (const float*)d_in[22];
  const float* s_w2   = (const float*)d_in[23];
  const float* s_b2   = (const float*)d_in[24];
  const float* s_wo   = (const float*)d_in[25];
  const float* s_bo   = (const float*)d_in[26];

  unsigned short* fs  = (unsigned short*)d_ws;
  unsigned short* cs  = fs + (size_t)NPTS * 32;
  unsigned short* ss  = cs + (size_t)NPTS * 32;
  unsigned short* w0b = ss + (size_t)NPTS * 32;
  unsigned short* w1b = w0b + 8192;
  unsigned short* w2b = w1b + 65536;
  unsigned short* wob = w2b + 65536;

  ResArr res;
  double kk = (log(2048.0) - log(16.0)) / 15.0;
  for (int l = 0; l < 16; ++l) res.r[l] = (float)floor(16.0 * exp((double)l * kk));

  float* out = (float*)d_out;

  hipLaunchKernelGGL(cvt_kernel, dim3(256), dim3(256), 0, stream,
                     s_w0, s_w1, s_w2, s_wo, w0b, w1b, w2b, wob);
  hipLaunchKernelGGL(hash_kernel, dim3(3072), dim3(256), 0, stream,
                     p, bound, t_sdf, t_color, t_sem, fs, cs, ss, out, res);
  hipLaunchKernelGGL(mlp_small_kernel, dim3(1024), dim3(256), 0, stream,
                     fs, cs, ss, f_w0, f_b0, f_w1, f_b1, f_w2, f_b2, f_w3, f_b3,
                     osdf_w, osdf_b, orgb_w0, orgb_b0, orgb_w1, orgb_b1, out);
  hipLaunchKernelGGL(sem_kernel, dim3(NPTS / 64), dim3(256), 0, stream,
                     ss, w0b, w1b, w2b, wob, s_b0, s_b1, s_b2, s_bo, out);
}

// Round 2
// 930.092 us; speedup vs baseline: 1.2842x; 1.2842x over previous
//
#include <hip/hip_runtime.h>
#include <math.h>

#define NPTS 262144
#define TTAB 524288
#define TMASK (TTAB - 1)
#define PR1 2654435761u
#define PR2 805459861u
#define SLOTS_PER_QUEUE 1536   // 6 pairs * 256 chunks
#define HASH_BLOCKS (8 * SLOTS_PER_QUEUE)

typedef __attribute__((ext_vector_type(4))) float f32x4;
typedef __attribute__((ext_vector_type(8))) short bf16x8;

struct ResArr { float r[16]; };

__device__ __forceinline__ float bf2f(unsigned int u) {
  union { unsigned int i; float f; } v; v.i = u << 16; return v.f;
}
__device__ __forceinline__ unsigned short f2bf(float f) {
  union { float f; unsigned int i; } v; v.f = f;
  unsigned int r = v.i + 0x7FFFu + ((v.i >> 16) & 1u);
  return (unsigned short)(r >> 16);
}
__device__ __forceinline__ unsigned int pack2(float a, float b) {
  return (unsigned int)f2bf(a) | ((unsigned int)f2bf(b) << 16);
}

// ---------------------------------------------------------------------------
__global__ void zero_ctr(unsigned int* c) { c[threadIdx.x] = 0u; }

// ---------------------------------------------------------------------------
// Table fp32 -> packed bf16 (bf16-table path only)
// ---------------------------------------------------------------------------
__global__ __launch_bounds__(256) void cvt_tab(
    const float* __restrict__ t0, const float* __restrict__ t1,
    const float* __restrict__ t2, unsigned int* __restrict__ tb16)
{
  size_t g = (size_t)blockIdx.x * 256 + threadIdx.x;  // groups of 4 entries
  size_t e = g * 4;
  unsigned int tab = (unsigned int)(e >> 23);          // 8388608 entries/table
  size_t off = e & ((16u * (size_t)TTAB) - 1);
  const float* src = ((tab == 0) ? t0 : (tab == 1) ? t1 : t2) + off * 2;
  float4 v0 = *(const float4*)(src);
  float4 v1 = *(const float4*)(src + 4);
  uint4 o;
  o.x = pack2(v0.x, v0.y);
  o.y = pack2(v0.z, v0.w);
  o.z = pack2(v1.x, v1.y);
  o.w = pack2(v1.z, v1.w);
  *(uint4*)(tb16 + e) = o;
}

// ---------------------------------------------------------------------------
// Hash gather: one (table,level) pair per block-claim, XCD-affine work queues.
// Writes level-major packed-bf16 features: featws[(table*16+level)*NPTS + n].
// ---------------------------------------------------------------------------
template <bool BT>
__global__ __launch_bounds__(256) void hash_kernel(
    const float* __restrict__ p, const float* __restrict__ bound,
    const float* __restrict__ t0, const float* __restrict__ t1,
    const float* __restrict__ t2, const unsigned int* __restrict__ tb16,
    unsigned int* __restrict__ featws, unsigned int* __restrict__ ctr,
    ResArr res)
{
  // fp32-table path: 40KB LDS pad caps occupancy at 4 blocks/CU so the
  // in-flight slot window stays within ~1.5 tables of L2 working set.
  __shared__ int s_slot_arr[BT ? 16 : 10240];
  if (threadIdx.x == 0) {
    unsigned int xcc;
    asm volatile("s_getreg_b32 %0, hwreg(HW_REG_XCC_ID)" : "=s"(xcc));
    xcc &= 7u;
    int slot = -1;
    for (int k = 0; k < 8; ++k) {
      unsigned int q = (xcc + (unsigned int)k) & 7u;
      unsigned int s = atomicAdd(ctr + q, 1u);
      if (s < SLOTS_PER_QUEUE) { slot = (int)(q * SLOTS_PER_QUEUE + s); break; }
    }
    s_slot_arr[0] = slot;
  }
  __syncthreads();
  int slot = s_slot_arr[0];
  if (slot < 0) return;

  unsigned int q = (unsigned int)slot / SLOTS_PER_QUEUE;
  unsigned int s = (unsigned int)slot - q * SLOTS_PER_QUEUE;
  unsigned int lp = s >> 8;            // local pair 0..5
  unsigned int i = lp * 8u + q;        // sorted pair index 0..47 (= level*3+table)
  unsigned int level = i / 3u;
  unsigned int table = i - level * 3u;
  unsigned int chunk = s & 255u;

  float r = res.r[0];
#pragma unroll
  for (int l = 1; l < 16; ++l) r = (level == (unsigned int)l) ? res.r[l] : r;

  float b0 = bound[0], b1 = bound[1], b2 = bound[2], b3 = bound[3],
        b4 = bound[4], b5 = bound[5];
  const float* tf = ((table == 0u) ? t0 : (table == 1u) ? t1 : t2) +
                    (size_t)level * (TTAB * 2);
  const unsigned int* tbf = tb16 + (size_t)(table * 16u + level) * TTAB;
  unsigned int fbase = (table * 16u + level) * (unsigned int)NPTS;
  unsigned int nbase = chunk * 1024u + threadIdx.x;

#pragma unroll
  for (int it = 0; it < 4; ++it) {
    unsigned int n = nbase + (unsigned int)it * 256u;
    float px = p[n * 3 + 0], py = p[n * 3 + 1], pz = p[n * 3 + 2];
    float x = (px - b0) / (b1 - b0);
    float y = (py - b2) / (b3 - b2);
    float z = (pz - b4) / (b5 - b4);
    float sx = x * r, sy = y * r, sz = z * r;
    float fx = floorf(sx), fy = floorf(sy), fz = floorf(sz);
    float dx = sx - fx, dy = sy - fy, dz = sz - fz;
    unsigned int cx = (unsigned int)fx, cy = (unsigned int)fy, cz = (unsigned int)fz;
    unsigned int hx[2] = { cx, cx + 1u };
    unsigned int hy[2] = { cy * PR1, (cy + 1u) * PR1 };
    unsigned int hz[2] = { cz * PR2, (cz + 1u) * PR2 };
    float wx[2] = { 1.f - dx, dx }, wy[2] = { 1.f - dy, dy }, wz[2] = { 1.f - dz, dz };
    float a0 = 0.f, a1 = 0.f;
#pragma unroll
    for (int ii = 0; ii < 2; ++ii)
#pragma unroll
      for (int jj = 0; jj < 2; ++jj)
#pragma unroll
        for (int kk = 0; kk < 2; ++kk) {
          unsigned int idx = (hx[ii] ^ hy[jj] ^ hz[kk]) & TMASK;
          float e0, e1;
          if (BT) {
            unsigned int u = tbf[idx];
            e0 = bf2f(u & 0xFFFFu);
            e1 = bf2f(u >> 16);
          } else {
            float2 f2 = *(const float2*)(tf + (size_t)idx * 2);
            e0 = f2.x; e1 = f2.y;
          }
          float w = wx[ii] * wy[jj] * wz[kk];
          a0 += e0 * w;
          a1 += e1 * w;
        }
    featws[fbase + n] = pack2(a0, a1);
  }
}

// ---------------------------------------------------------------------------
// Small MLPs (sdf chain + rgb) + plane_feat writeout. One thread per point.
// ---------------------------------------------------------------------------
__global__ __launch_bounds__(256) void mlp_small_kernel(
    const unsigned int* __restrict__ fws,
    const float* __restrict__ fw0, const float* __restrict__ fb0,
    const float* __restrict__ fw1, const float* __restrict__ fb1,
    const float* __restrict__ fw2, const float* __restrict__ fb2,
    const float* __restrict__ fw3, const float* __restrict__ fb3,
    const float* __restrict__ ow, const float* __restrict__ ob,
    const float* __restrict__ rw0, const float* __restrict__ rb0,
    const float* __restrict__ rw1, const float* __restrict__ rb1,
    float* __restrict__ out)
{
  unsigned int n = blockIdx.x * 256 + threadIdx.x;
  float ft[32], cf[32], sf[32];
#pragma unroll
  for (int l = 0; l < 16; ++l) {
    unsigned int u = fws[(0u * 16 + l) * (unsigned int)NPTS + n];
    ft[2 * l] = bf2f(u & 0xFFFFu); ft[2 * l + 1] = bf2f(u >> 16);
    u = fws[(1u * 16 + l) * (unsigned int)NPTS + n];
    cf[2 * l] = bf2f(u & 0xFFFFu); cf[2 * l + 1] = bf2f(u >> 16);
    u = fws[(2u * 16 + l) * (unsigned int)NPTS + n];
    sf[2 * l] = bf2f(u & 0xFFFFu); sf[2 * l + 1] = bf2f(u >> 16);
  }

  // plane_feat = [c_feat[16:], f_feat[16:], s_feat[16:]] fp32
  {
    float* pf = out + (size_t)NPTS * 29 + (size_t)n * 48;
#pragma unroll
    for (int i2 = 0; i2 < 16; i2 += 4)
      *(float4*)(pf + i2) = make_float4(cf[16 + i2], cf[17 + i2], cf[18 + i2], cf[19 + i2]);
#pragma unroll
    for (int i2 = 0; i2 < 16; i2 += 4)
      *(float4*)(pf + 16 + i2) = make_float4(ft[16 + i2], ft[17 + i2], ft[18 + i2], ft[19 + i2]);
#pragma unroll
    for (int i2 = 0; i2 < 16; i2 += 4)
      *(float4*)(pf + 32 + i2) = make_float4(sf[16 + i2], sf[17 + i2], sf[18 + i2], sf[19 + i2]);
  }

  float h[16], g[16];
  for (int o = 0; o < 16; ++o) {
    float a = fb0[o];
    for (int i2 = 0; i2 < 32; ++i2) a += ft[i2] * fw0[o * 32 + i2];
    h[o] = fmaxf(a, 0.f);
  }
  for (int o = 0; o < 16; ++o) {
    float a = fb1[o];
    for (int i2 = 0; i2 < 16; ++i2) a += h[i2] * fw1[o * 16 + i2];
    g[o] = fmaxf(a, 0.f);
  }
  for (int o = 0; o < 16; ++o) {
    float a = fb2[o];
    for (int i2 = 0; i2 < 16; ++i2) a += g[i2] * fw2[o * 16 + i2];
    h[o] = fmaxf(a, 0.f);
  }
  for (int o = 0; o < 16; ++o) {
    float a = fb3[o];
    for (int i2 = 0; i2 < 16; ++i2) a += h[i2] * fw3[o * 16 + i2];
    g[o] = fmaxf(a, 0.f);
  }
  float so[17];
  for (int o = 0; o < 17; ++o) {
    float a = ob[o];
    for (int i2 = 0; i2 < 16; ++i2) a += g[i2] * ow[o * 16 + i2];
    so[o] = a;
  }
  float sdf = tanhf(so[0]);
  float rin[80];
#pragma unroll
  for (int i2 = 0; i2 < 16; ++i2) rin[i2] = so[i2 + 1];
#pragma unroll
  for (int i2 = 0; i2 < 32; ++i2) rin[16 + i2] = cf[i2];
#pragma unroll
  for (int i2 = 0; i2 < 32; ++i2) rin[48 + i2] = sf[i2];
  float hr[16];
  for (int o = 0; o < 16; ++o) {
    float a = rb0[o];
    for (int i2 = 0; i2 < 80; ++i2) a += rin[i2] * rw0[o * 80 + i2];
    hr[o] = fmaxf(a, 0.f);
  }
  float* po = out + (size_t)n * 29;
  for (int o = 0; o < 3; ++o) {
    float a = rb1[o];
    for (int i2 = 0; i2 < 16; ++i2) a += hr[i2] * rw1[o * 16 + i2];
    po[o] = 1.f / (1.f + expf(-a));
  }
  po[3] = sdf;
}

// ---------------------------------------------------------------------------
// Weight fp32 -> bf16 (semantic MLP weights; wo zero-padded 25->32 rows)
// ---------------------------------------------------------------------------
__global__ __launch_bounds__(256) void cvt_kernel(
    const float* __restrict__ sw0, const float* __restrict__ sw1,
    const float* __restrict__ sw2, const float* __restrict__ swo,
    unsigned short* __restrict__ w0, unsigned short* __restrict__ w1,
    unsigned short* __restrict__ w2, unsigned short* __restrict__ wo)
{
  int t = blockIdx.x * 256 + threadIdx.x;   // grid covers 65536
  if (t < 8192) w0[t] = f2bf(sw0[t]);
  w1[t] = f2bf(sw1[t]);
  w2[t] = f2bf(sw2[t]);
  if (t < 8192) wo[t] = (t < 6400) ? f2bf(swo[t]) : (unsigned short)0;
}

// ---------------------------------------------------------------------------
// Semantic MLP 32->256->256->256->25 via bf16 MFMA 16x16x32.
// ---------------------------------------------------------------------------
#define LAYER256(Hin, Wp, Bp, Hout)                                                        \
  {                                                                                        \
    _Pragma("unroll") for (int r = 0; r < 4; ++r)                                          \
      _Pragma("unroll") for (int c = 0; c < 4; ++c)                                        \
        acc[r][c] = (f32x4){0.f, 0.f, 0.f, 0.f};                                           \
    _Pragma("unroll") for (int ks = 0; ks < 8; ++ks) {                                     \
      int k0 = ks * 32;                                                                    \
      _Pragma("unroll") for (int r = 0; r < 4; ++r)                                        \
        a[r] = *(const bf16x8*)(Hin + (r * 16 + l16) * 264 + k0 + quad * 8);               \
      _Pragma("unroll") for (int c = 0; c < 4; ++c)                                        \
        b[c] = *(const bf16x8*)(Wp + (size_t)(cw + c * 16 + l16) * 256 + k0 + quad * 8);   \
      _Pragma("unroll") for (int r = 0; r < 4; ++r)                                        \
        _Pragma("unroll") for (int c = 0; c < 4; ++c)                                      \
          acc[r][c] = __builtin_amdgcn_mfma_f32_16x16x32_bf16(a[r], b[c], acc[r][c], 0, 0, 0); \
    }                                                                                      \
    _Pragma("unroll") for (int c = 0; c < 4; ++c) {                                        \
      int col = cw + c * 16 + l16;                                                         \
      float bias = Bp[col];                                                                \
      _Pragma("unroll") for (int r = 0; r < 4; ++r)                                        \
        _Pragma("unroll") for (int g2 = 0; g2 < 4; ++g2) {                                 \
          int row = r * 16 + quad * 4 + g2;                                                \
          Hout[row * 264 + col] = f2bf(fmaxf(acc[r][c][g2] + bias, 0.f));                  \
        }                                                                                  \
    }                                                                                      \
    __syncthreads();                                                                       \
  }

__global__ __launch_bounds__(256) void sem_kernel(
    const unsigned int* __restrict__ fws,
    const unsigned short* __restrict__ w0, const unsigned short* __restrict__ w1,
    const unsigned short* __restrict__ w2, const unsigned short* __restrict__ wo,
    const float* __restrict__ b0, const float* __restrict__ b1,
    const float* __restrict__ b2, const float* __restrict__ bo,
    float* __restrict__ out)
{
  __shared__ alignas(16) unsigned short X[64 * 40];
  __shared__ alignas(16) unsigned short HA[64 * 264];
  __shared__ alignas(16) unsigned short HB[64 * 264];

  int tid = threadIdx.x;
  int n0 = blockIdx.x * 64;
  int lane = tid & 63, wv = tid >> 6;
  int l16 = lane & 15, quad = lane >> 4;
  int cw = wv * 64;

  {
    int t = tid & 63;
    int lbase = tid >> 6;
#pragma unroll
    for (int it = 0; it < 4; ++it) {
      int l = lbase * 4 + it;
      unsigned int v = fws[(2u * 16 + l) * (unsigned int)NPTS + (unsigned int)(n0 + t)];
      *(unsigned int*)(X + t * 40 + 2 * l) = v;
    }
  }
  __syncthreads();

  f32x4 acc[4][4];
  bf16x8 a[4], b[4];

  // ---- layer 0 (K=32): X @ W0^T -> HA ----
#pragma unroll
  for (int r = 0; r < 4; ++r)
#pragma unroll
    for (int c = 0; c < 4; ++c) acc[r][c] = (f32x4){0.f, 0.f, 0.f, 0.f};
#pragma unroll
  for (int r = 0; r < 4; ++r) a[r] = *(const bf16x8*)(X + (r * 16 + l16) * 40 + quad * 8);
#pragma unroll
  for (int c = 0; c < 4; ++c) b[c] = *(const bf16x8*)(w0 + (size_t)(cw + c * 16 + l16) * 32 + quad * 8);
#pragma unroll
  for (int r = 0; r < 4; ++r)
#pragma unroll
    for (int c = 0; c < 4; ++c)
      acc[r][c] = __builtin_amdgcn_mfma_f32_16x16x32_bf16(a[r], b[c], acc[r][c], 0, 0, 0);
#pragma unroll
  for (int c = 0; c < 4; ++c) {
    int col = cw + c * 16 + l16;
    float bias = b0[col];
#pragma unroll
    for (int r = 0; r < 4; ++r)
#pragma unroll
      for (int g2 = 0; g2 < 4; ++g2) {
        int row = r * 16 + quad * 4 + g2;
        HA[row * 264 + col] = f2bf(fmaxf(acc[r][c][g2] + bias, 0.f));
      }
  }
  __syncthreads();

  // ---- layer 1: HA @ W1^T -> HB ----
  LAYER256(HA, w1, b1, HB)
  // ---- layer 2: HB @ W2^T -> HA ----
  LAYER256(HB, w2, b2, HA)

  // ---- output layer (25 cols): HA @ Wo^T -> d_out ----
  f32x4 acc2[2];
  acc2[0] = (f32x4){0.f, 0.f, 0.f, 0.f};
  acc2[1] = (f32x4){0.f, 0.f, 0.f, 0.f};
#pragma unroll
  for (int ks = 0; ks < 8; ++ks) {
    int k0 = ks * 32;
    bf16x8 af = *(const bf16x8*)(HA + (wv * 16 + l16) * 264 + k0 + quad * 8);
#pragma unroll
    for (int c = 0; c < 2; ++c) {
      bf16x8 bf = *(const bf16x8*)(wo + (size_t)(c * 16 + l16) * 256 + k0 + quad * 8);
      acc2[c] = __builtin_amdgcn_mfma_f32_16x16x32_bf16(af, bf, acc2[c], 0, 0, 0);
    }
  }
#pragma unroll
  for (int c = 0; c < 2; ++c) {
    int col = c * 16 + l16;
    if (col < 25) {
      float bias = bo[col];
#pragma unroll
      for (int g2 = 0; g2 < 4; ++g2) {
        int row = wv * 16 + quad * 4 + g2;
        out[(size_t)(n0 + row) * 29 + 4 + col] = acc2[c][g2] + bias;
      }
    }
  }
}

// ---------------------------------------------------------------------------
extern "C" void kernel_launch(void* const* d_in, const int* in_sizes, int n_in,
                              void* d_out, int out_size, void* d_ws, size_t ws_size,
                              hipStream_t stream) {
  const float* p      = (const float*)d_in[0];
  const float* bound  = (const float*)d_in[1];
  const float* t_sdf  = (const float*)d_in[2];
  const float* t_color= (const float*)d_in[3];
  const float* t_sem  = (const float*)d_in[4];
  const float* f_w0   = (const float*)d_in[5];
  const float* f_b0   = (const float*)d_in[6];
  const float* f_w1   = (const float*)d_in[7];
  const float* f_b1   = (const float*)d_in[8];
  const float* f_w2   = (const float*)d_in[9];
  const float* f_b2   = (const float*)d_in[10];
  const float* f_w3   = (const float*)d_in[11];
  const float* f_b3   = (const float*)d_in[12];
  const float* osdf_w = (const float*)d_in[13];
  const float* osdf_b = (const float*)d_in[14];
  const float* orgb_w0= (const float*)d_in[15];
  const float* orgb_b0= (const float*)d_in[16];
  const float* orgb_w1= (const float*)d_in[17];
  const float* orgb_b1= (const float*)d_in[18];
  const float* s_w0   = (const float*)d_in[19];
  const float* s_b0   = (const float*)d_in[20];
  const float* s_w1   = (const float*)d_in[21];
  const float* s_b1   = (const float*)d_in[22];
  const float* s_w2   = (const float*)d_in[23];
  const float* s_b2   = (const float*)d_in[24];
  const float* s_wo   = (const float*)d_in[25];
  const float* s_bo   = (const float*)d_in[26];

  unsigned int* featws = (unsigned int*)d_ws;                  // 48*N*4 = 50,331,648 B
  unsigned short* w0b = (unsigned short*)(featws + 48u * NPTS);
  unsigned short* w1b = w0b + 8192;
  unsigned short* w2b = w1b + 65536;
  unsigned short* wob = w2b + 65536;
  unsigned int* ctr = (unsigned int*)(wob + 8192);             // 32 B, 16-aligned
  unsigned int* tb16 = ctr + 8;                                // 100,663,296 B
  size_t need_bt = ((char*)tb16 - (char*)d_ws) + (size_t)48 * TTAB * 4;
  bool use_bt = ws_size >= need_bt;

  ResArr res;
  double kk = (log(2048.0) - log(16.0)) / 15.0;
  for (int l = 0; l < 16; ++l) res.r[l] = (float)floor(16.0 * exp((double)l * kk));

  float* out = (float*)d_out;

  hipLaunchKernelGGL(zero_ctr, dim3(1), dim3(8), 0, stream, ctr);
  hipLaunchKernelGGL(cvt_kernel, dim3(256), dim3(256), 0, stream,
                     s_w0, s_w1, s_w2, s_wo, w0b, w1b, w2b, wob);
  if (use_bt) {
    hipLaunchKernelGGL(cvt_tab, dim3(24576), dim3(256), 0, stream,
                       t_sdf, t_color, t_sem, tb16);
    hipLaunchKernelGGL(hash_kernel<true>, dim3(HASH_BLOCKS), dim3(256), 0, stream,
                       p, bound, t_sdf, t_color, t_sem, tb16, featws, ctr, res);
  } else {
    hipLaunchKernelGGL(hash_kernel<false>, dim3(HASH_BLOCKS), dim3(256), 0, stream,
                       p, bound, t_sdf, t_color, t_sem, tb16, featws, ctr, res);
  }
  hipLaunchKernelGGL(mlp_small_kernel, dim3(1024), dim3(256), 0, stream,
                     featws, f_w0, f_b0, f_w1, f_b1, f_w2, f_b2, f_w3, f_b3,
                     osdf_w, osdf_b, orgb_w0, orgb_b0, orgb_w1, orgb_b1, out);
  hipLaunchKernelGGL(sem_kernel, dim3(NPTS / 64), dim3(256), 0, stream,
                     featws, w0b, w1b, w2b, wob, s_b0, s_b1, s_b2, s_bo, out);
}

// Round 3
// 852.882 us; speedup vs baseline: 1.4004x; 1.0905x over previous
//
#include <hip/hip_runtime.h>
#include <math.h>

#define NPTS 262144
#define TTAB 524288
#define TMASK (TTAB - 1)
#define PR1 2654435761u
#define PR2 805459861u
#define SLOTS_PER_QUEUE 1536   // 6 pairs * 256 chunks
#define HASH_BLOCKS (8 * SLOTS_PER_QUEUE)

typedef __attribute__((ext_vector_type(4))) float f32x4;
typedef __attribute__((ext_vector_type(8))) short bf16x8;

struct ResArr { float r[16]; };

__device__ __forceinline__ float bf2f(unsigned int u) {
  union { unsigned int i; float f; } v; v.i = u << 16; return v.f;
}
__device__ __forceinline__ unsigned short f2bf(float f) {
  union { float f; unsigned int i; } v; v.f = f;
  unsigned int r = v.i + 0x7FFFu + ((v.i >> 16) & 1u);
  return (unsigned short)(r >> 16);
}
__device__ __forceinline__ unsigned int pack2(float a, float b) {
  return (unsigned int)f2bf(a) | ((unsigned int)f2bf(b) << 16);
}

// ---------------------------------------------------------------------------
// Table fp32 -> packed bf16 (bf16-table path only)
// ---------------------------------------------------------------------------
__global__ __launch_bounds__(256) void cvt_tab(
    const float* __restrict__ t0, const float* __restrict__ t1,
    const float* __restrict__ t2, unsigned int* __restrict__ tb16)
{
  size_t g = (size_t)blockIdx.x * 256 + threadIdx.x;  // groups of 4 entries
  size_t e = g * 4;
  unsigned int tab = (unsigned int)(e >> 23);          // 8388608 entries/table
  size_t off = e & ((16u * (size_t)TTAB) - 1);
  const float* src = ((tab == 0) ? t0 : (tab == 1) ? t1 : t2) + off * 2;
  float4 v0 = *(const float4*)(src);
  float4 v1 = *(const float4*)(src + 4);
  uint4 o;
  o.x = pack2(v0.x, v0.y);
  o.y = pack2(v0.z, v0.w);
  o.z = pack2(v1.x, v1.y);
  o.w = pack2(v1.z, v1.w);
  *(uint4*)(tb16 + e) = o;
}

// ---------------------------------------------------------------------------
// Hash gather: one (table,level) pair per block-claim, XCD-affine work queues.
// 3-phase structure: addresses -> 32 batched gathers -> accumulate, to
// maximize outstanding loads per wave (L2-latency-bound regime).
// Writes level-major packed-bf16 features: featws[(table*16+level)*NPTS + n].
// ---------------------------------------------------------------------------
template <bool BT>
__global__ __launch_bounds__(256) void hash_kernel(
    const float* __restrict__ p, const float* __restrict__ bound,
    const float* __restrict__ t0, const float* __restrict__ t1,
    const float* __restrict__ t2, const unsigned int* __restrict__ tb16,
    unsigned int* __restrict__ featws, unsigned int* __restrict__ ctr,
    ResArr res)
{
  // fp32-table path: 40KB LDS pad caps occupancy so the in-flight slot
  // window stays within ~1.5 tables of L2 working set.
  __shared__ int s_slot_arr[BT ? 16 : 10240];
  if (threadIdx.x == 0) {
    unsigned int xcc;
    asm volatile("s_getreg_b32 %0, hwreg(HW_REG_XCC_ID)" : "=s"(xcc));
    xcc &= 7u;
    int slot = -1;
    for (int k = 0; k < 8; ++k) {
      unsigned int q = (xcc + (unsigned int)k) & 7u;
      unsigned int s = atomicAdd(ctr + q, 1u);
      if (s < SLOTS_PER_QUEUE) { slot = (int)(q * SLOTS_PER_QUEUE + s); break; }
    }
    s_slot_arr[0] = slot;
  }
  __syncthreads();
  int slot = s_slot_arr[0];
  if (slot < 0) return;

  unsigned int q = (unsigned int)slot / SLOTS_PER_QUEUE;
  unsigned int s = (unsigned int)slot - q * SLOTS_PER_QUEUE;
  unsigned int lp = s >> 8;            // local pair 0..5
  unsigned int i = lp * 8u + q;        // sorted pair index 0..47 (= level*3+table)
  unsigned int level = i / 3u;
  unsigned int table = i - level * 3u;
  unsigned int chunk = s & 255u;

  float r = res.r[0];
#pragma unroll
  for (int l = 1; l < 16; ++l) r = (level == (unsigned int)l) ? res.r[l] : r;

  float b0 = bound[0], b1 = bound[1], b2 = bound[2], b3 = bound[3],
        b4 = bound[4], b5 = bound[5];
  float i0v = 1.f / (b1 - b0), i1v = 1.f / (b3 - b2), i2v = 1.f / (b5 - b4);
  const float* tf = ((table == 0u) ? t0 : (table == 1u) ? t1 : t2) +
                    (size_t)level * (TTAB * 2);
  const unsigned int* tbf = tb16 + (size_t)(table * 16u + level) * TTAB;
  unsigned int fbase = (table * 16u + level) * (unsigned int)NPTS;
  unsigned int nbase = chunk * 1024u + threadIdx.x;

  unsigned int CX[4], CY[4], CZ[4];
  float DX[4], DY[4], DZ[4];

  // phase A: point loads + cell scalars (4 points)
#pragma unroll
  for (int pt = 0; pt < 4; ++pt) {
    unsigned int n = nbase + (unsigned int)pt * 256u;
    float px = p[n * 3 + 0], py = p[n * 3 + 1], pz = p[n * 3 + 2];
    float sx = (px - b0) * i0v * r;
    float sy = (py - b2) * i1v * r;
    float sz = (pz - b4) * i2v * r;
    float fx = floorf(sx), fy = floorf(sy), fz = floorf(sz);
    DX[pt] = sx - fx; DY[pt] = sy - fy; DZ[pt] = sz - fz;
    CX[pt] = (unsigned int)fx;
    CY[pt] = (unsigned int)fy * PR1;
    CZ[pt] = (unsigned int)fz * PR2;
  }
  __builtin_amdgcn_sched_barrier(0);

  // phase B: issue all 32 gathers
  unsigned int V[4][8];
  float2 Vf[4][8];
#pragma unroll
  for (int pt = 0; pt < 4; ++pt) {
    unsigned int x0 = CX[pt], x1 = CX[pt] + 1u;
    unsigned int y0 = CY[pt], y1 = y0 + PR1;
    unsigned int z0 = CZ[pt], z1 = z0 + PR2;
    unsigned int id[8];
    id[0] = (x0 ^ y0 ^ z0) & TMASK;
    id[1] = (x0 ^ y0 ^ z1) & TMASK;
    id[2] = (x0 ^ y1 ^ z0) & TMASK;
    id[3] = (x0 ^ y1 ^ z1) & TMASK;
    id[4] = (x1 ^ y0 ^ z0) & TMASK;
    id[5] = (x1 ^ y0 ^ z1) & TMASK;
    id[6] = (x1 ^ y1 ^ z0) & TMASK;
    id[7] = (x1 ^ y1 ^ z1) & TMASK;
#pragma unroll
    for (int c = 0; c < 8; ++c) {
      if (BT) V[pt][c] = tbf[id[c]];
      else    Vf[pt][c] = *(const float2*)(tf + (size_t)id[c] * 2);
    }
  }
  __builtin_amdgcn_sched_barrier(0);

  // phase C: accumulate + store
#pragma unroll
  for (int pt = 0; pt < 4; ++pt) {
    float dx = DX[pt], dy = DY[pt], dz = DZ[pt];
    float wx[2] = { 1.f - dx, dx }, wy[2] = { 1.f - dy, dy }, wz[2] = { 1.f - dz, dz };
    float a0 = 0.f, a1 = 0.f;
#pragma unroll
    for (int c = 0; c < 8; ++c) {
      float w = wx[c >> 2] * wy[(c >> 1) & 1] * wz[c & 1];
      float e0, e1;
      if (BT) { unsigned int u = V[pt][c]; e0 = bf2f(u & 0xFFFFu); e1 = bf2f(u >> 16); }
      else    { e0 = Vf[pt][c].x; e1 = Vf[pt][c].y; }
      a0 += e0 * w;
      a1 += e1 * w;
    }
    unsigned int n = nbase + (unsigned int)pt * 256u;
    featws[fbase + n] = pack2(a0, a1);
  }
}

// ---------------------------------------------------------------------------
// Small MLPs (sdf chain + rgb) + plane_feat writeout. One thread per point.
// ---------------------------------------------------------------------------
__global__ __launch_bounds__(256) void mlp_small_kernel(
    const unsigned int* __restrict__ fws,
    const float* __restrict__ fw0, const float* __restrict__ fb0,
    const float* __restrict__ fw1, const float* __restrict__ fb1,
    const float* __restrict__ fw2, const float* __restrict__ fb2,
    const float* __restrict__ fw3, const float* __restrict__ fb3,
    const float* __restrict__ ow, const float* __restrict__ ob,
    const float* __restrict__ rw0, const float* __restrict__ rb0,
    const float* __restrict__ rw1, const float* __restrict__ rb1,
    float* __restrict__ out)
{
  unsigned int n = blockIdx.x * 256 + threadIdx.x;
  float ft[32], cf[32], sf[32];
#pragma unroll
  for (int l = 0; l < 16; ++l) {
    unsigned int u = fws[(0u * 16 + l) * (unsigned int)NPTS + n];
    ft[2 * l] = bf2f(u & 0xFFFFu); ft[2 * l + 1] = bf2f(u >> 16);
    u = fws[(1u * 16 + l) * (unsigned int)NPTS + n];
    cf[2 * l] = bf2f(u & 0xFFFFu); cf[2 * l + 1] = bf2f(u >> 16);
    u = fws[(2u * 16 + l) * (unsigned int)NPTS + n];
    sf[2 * l] = bf2f(u & 0xFFFFu); sf[2 * l + 1] = bf2f(u >> 16);
  }

  // plane_feat = [c_feat[16:], f_feat[16:], s_feat[16:]] fp32
  {
    float* pf = out + (size_t)NPTS * 29 + (size_t)n * 48;
#pragma unroll
    for (int i2 = 0; i2 < 16; i2 += 4)
      *(float4*)(pf + i2) = make_float4(cf[16 + i2], cf[17 + i2], cf[18 + i2], cf[19 + i2]);
#pragma unroll
    for (int i2 = 0; i2 < 16; i2 += 4)
      *(float4*)(pf + 16 + i2) = make_float4(ft[16 + i2], ft[17 + i2], ft[18 + i2], ft[19 + i2]);
#pragma unroll
    for (int i2 = 0; i2 < 16; i2 += 4)
      *(float4*)(pf + 32 + i2) = make_float4(sf[16 + i2], sf[17 + i2], sf[18 + i2], sf[19 + i2]);
  }

  float h[16], g[16];
  for (int o = 0; o < 16; ++o) {
    float a = fb0[o];
    for (int i2 = 0; i2 < 32; ++i2) a += ft[i2] * fw0[o * 32 + i2];
    h[o] = fmaxf(a, 0.f);
  }
  for (int o = 0; o < 16; ++o) {
    float a = fb1[o];
    for (int i2 = 0; i2 < 16; ++i2) a += h[i2] * fw1[o * 16 + i2];
    g[o] = fmaxf(a, 0.f);
  }
  for (int o = 0; o < 16; ++o) {
    float a = fb2[o];
    for (int i2 = 0; i2 < 16; ++i2) a += g[i2] * fw2[o * 16 + i2];
    h[o] = fmaxf(a, 0.f);
  }
  for (int o = 0; o < 16; ++o) {
    float a = fb3[o];
    for (int i2 = 0; i2 < 16; ++i2) a += h[i2] * fw3[o * 16 + i2];
    g[o] = fmaxf(a, 0.f);
  }
  float so[17];
  for (int o = 0; o < 17; ++o) {
    float a = ob[o];
    for (int i2 = 0; i2 < 16; ++i2) a += g[i2] * ow[o * 16 + i2];
    so[o] = a;
  }
  float sdf = tanhf(so[0]);
  float rin[80];
#pragma unroll
  for (int i2 = 0; i2 < 16; ++i2) rin[i2] = so[i2 + 1];
#pragma unroll
  for (int i2 = 0; i2 < 32; ++i2) rin[16 + i2] = cf[i2];
#pragma unroll
  for (int i2 = 0; i2 < 32; ++i2) rin[48 + i2] = sf[i2];
  float hr[16];
  for (int o = 0; o < 16; ++o) {
    float a = rb0[o];
    for (int i2 = 0; i2 < 80; ++i2) a += rin[i2] * rw0[o * 80 + i2];
    hr[o] = fmaxf(a, 0.f);
  }
  float* po = out + (size_t)n * 29;
  for (int o = 0; o < 3; ++o) {
    float a = rb1[o];
    for (int i2 = 0; i2 < 16; ++i2) a += hr[i2] * rw1[o * 16 + i2];
    po[o] = 1.f / (1.f + expf(-a));
  }
  po[3] = sdf;
}

// ---------------------------------------------------------------------------
// Weight fp32 -> bf16 (semantic MLP weights; wo zero-padded 25->32 rows)
// Also zeroes the 8 hash work-queue counters (one less launch).
// ---------------------------------------------------------------------------
__global__ __launch_bounds__(256) void cvt_kernel(
    const float* __restrict__ sw0, const float* __restrict__ sw1,
    const float* __restrict__ sw2, const float* __restrict__ swo,
    unsigned short* __restrict__ w0, unsigned short* __restrict__ w1,
    unsigned short* __restrict__ w2, unsigned short* __restrict__ wo,
    unsigned int* __restrict__ ctr)
{
  int t = blockIdx.x * 256 + threadIdx.x;   // grid covers 65536
  if (t < 8) ctr[t] = 0u;
  if (t < 8192) w0[t] = f2bf(sw0[t]);
  w1[t] = f2bf(sw1[t]);
  w2[t] = f2bf(sw2[t]);
  if (t < 8192) wo[t] = (t < 6400) ? f2bf(swo[t]) : (unsigned short)0;
}

// ---------------------------------------------------------------------------
// Semantic MLP 32->256->256->256->25 via bf16 MFMA 16x16x32.
// 512 threads / 8 waves per block; per-wave tile 64 rows x 32 cols.
// ---------------------------------------------------------------------------
#define LAYER256(Hin, Wp, Bp, Hout)                                                        \
  {                                                                                        \
    _Pragma("unroll") for (int r = 0; r < 4; ++r)                                          \
      _Pragma("unroll") for (int c = 0; c < 2; ++c)                                        \
        acc[r][c] = (f32x4){0.f, 0.f, 0.f, 0.f};                                           \
    _Pragma("unroll") for (int ks = 0; ks < 8; ++ks) {                                     \
      int k0 = ks * 32;                                                                    \
      _Pragma("unroll") for (int r = 0; r < 4; ++r)                                        \
        a[r] = *(const bf16x8*)(Hin + (r * 16 + l16) * 264 + k0 + quad * 8);               \
      _Pragma("unroll") for (int c = 0; c < 2; ++c)                                        \
        b[c] = *(const bf16x8*)(Wp + (size_t)(cw + c * 16 + l16) * 256 + k0 + quad * 8);   \
      _Pragma("unroll") for (int r = 0; r < 4; ++r)                                        \
        _Pragma("unroll") for (int c = 0; c < 2; ++c)                                      \
          acc[r][c] = __builtin_amdgcn_mfma_f32_16x16x32_bf16(a[r], b[c], acc[r][c], 0, 0, 0); \
    }                                                                                      \
    _Pragma("unroll") for (int c = 0; c < 2; ++c) {                                        \
      int col = cw + c * 16 + l16;                                                         \
      float bias = Bp[col];                                                                \
      _Pragma("unroll") for (int r = 0; r < 4; ++r)                                        \
        _Pragma("unroll") for (int g2 = 0; g2 < 4; ++g2) {                                 \
          int row = r * 16 + quad * 4 + g2;                                                \
          Hout[row * 264 + col] = f2bf(fmaxf(acc[r][c][g2] + bias, 0.f));                  \
        }                                                                                  \
    }                                                                                      \
    __syncthreads();                                                                       \
  }

__global__ __launch_bounds__(512) void sem_kernel(
    const unsigned int* __restrict__ fws,
    const unsigned short* __restrict__ w0, const unsigned short* __restrict__ w1,
    const unsigned short* __restrict__ w2, const unsigned short* __restrict__ wo,
    const float* __restrict__ b0, const float* __restrict__ b1,
    const float* __restrict__ b2, const float* __restrict__ bo,
    float* __restrict__ out)
{
  __shared__ alignas(16) unsigned short X[64 * 40];
  __shared__ alignas(16) unsigned short HA[64 * 264];
  __shared__ alignas(16) unsigned short HB[64 * 264];

  int tid = threadIdx.x;
  int n0 = blockIdx.x * 64;
  int lane = tid & 63, wv = tid >> 6;       // 8 waves
  int l16 = lane & 15, quad = lane >> 4;
  int cw = wv * 32;

  // stage X: 64 rows x 16 level-dwords
#pragma unroll
  for (int h = 0; h < 2; ++h) {
    int idx = tid + h * 512;
    int row = idx & 63;
    int l = idx >> 6;
    unsigned int v = fws[(32u + (unsigned int)l) * (unsigned int)NPTS + (unsigned int)(n0 + row)];
    *(unsigned int*)(X + row * 40 + 2 * l) = v;
  }
  __syncthreads();

  f32x4 acc[4][2];
  bf16x8 a[4], b[2];

  // ---- layer 0 (K=32): X @ W0^T -> HA ----
#pragma unroll
  for (int r = 0; r < 4; ++r)
#pragma unroll
    for (int c = 0; c < 2; ++c) acc[r][c] = (f32x4){0.f, 0.f, 0.f, 0.f};
#pragma unroll
  for (int r = 0; r < 4; ++r) a[r] = *(const bf16x8*)(X + (r * 16 + l16) * 40 + quad * 8);
#pragma unroll
  for (int c = 0; c < 2; ++c) b[c] = *(const bf16x8*)(w0 + (size_t)(cw + c * 16 + l16) * 32 + quad * 8);
#pragma unroll
  for (int r = 0; r < 4; ++r)
#pragma unroll
    for (int c = 0; c < 2; ++c)
      acc[r][c] = __builtin_amdgcn_mfma_f32_16x16x32_bf16(a[r], b[c], acc[r][c], 0, 0, 0);
#pragma unroll
  for (int c = 0; c < 2; ++c) {
    int col = cw + c * 16 + l16;
    float bias = b0[col];
#pragma unroll
    for (int r = 0; r < 4; ++r)
#pragma unroll
      for (int g2 = 0; g2 < 4; ++g2) {
        int row = r * 16 + quad * 4 + g2;
        HA[row * 264 + col] = f2bf(fmaxf(acc[r][c][g2] + bias, 0.f));
      }
  }
  __syncthreads();

  // ---- layer 1: HA @ W1^T -> HB ----
  LAYER256(HA, w1, b1, HB)
  // ---- layer 2: HB @ W2^T -> HA ----
  LAYER256(HB, w2, b2, HA)

  // ---- output layer (25 cols): HA @ Wo^T -> d_out ----
  // 8 waves: row-tile = wv>>1 (4), col-tile = wv&1 (2)
  {
    int rt = wv >> 1, ct = wv & 1;
    f32x4 acc2 = (f32x4){0.f, 0.f, 0.f, 0.f};
#pragma unroll
    for (int ks = 0; ks < 8; ++ks) {
      int k0 = ks * 32;
      bf16x8 af = *(const bf16x8*)(HA + (rt * 16 + l16) * 264 + k0 + quad * 8);
      bf16x8 bf = *(const bf16x8*)(wo + (size_t)(ct * 16 + l16) * 256 + k0 + quad * 8);
      acc2 = __builtin_amdgcn_mfma_f32_16x16x32_bf16(af, bf, acc2, 0, 0, 0);
    }
    int col = ct * 16 + l16;
    if (col < 25) {
      float bias = bo[col];
#pragma unroll
      for (int g2 = 0; g2 < 4; ++g2) {
        int row = rt * 16 + quad * 4 + g2;
        out[(size_t)(n0 + row) * 29 + 4 + col] = acc2[g2] + bias;
      }
    }
  }
}

// ---------------------------------------------------------------------------
extern "C" void kernel_launch(void* const* d_in, const int* in_sizes, int n_in,
                              void* d_out, int out_size, void* d_ws, size_t ws_size,
                              hipStream_t stream) {
  const float* p      = (const float*)d_in[0];
  const float* bound  = (const float*)d_in[1];
  const float* t_sdf  = (const float*)d_in[2];
  const float* t_color= (const float*)d_in[3];
  const float* t_sem  = (const float*)d_in[4];
  const float* f_w0   = (const float*)d_in[5];
  const float* f_b0   = (const float*)d_in[6];
  const float* f_w1   = (const float*)d_in[7];
  const float* f_b1   = (const float*)d_in[8];
  const float* f_w2   = (const float*)d_in[9];
  const float* f_b2   = (const float*)d_in[10];
  const float* f_w3   = (const float*)d_in[11];
  const float* f_b3   = (const float*)d_in[12];
  const float* osdf_w = (const float*)d_in[13];
  const float* osdf_b = (const float*)d_in[14];
  const float* orgb_w0= (const float*)d_in[15];
  const float* orgb_b0= (const float*)d_in[16];
  const float* orgb_w1= (const float*)d_in[17];
  const float* orgb_b1= (const float*)d_in[18];
  const float* s_w0   = (const float*)d_in[19];
  const float* s_b0   = (const float*)d_in[20];
  const float* s_w1   = (const float*)d_in[21];
  const float* s_b1   = (const float*)d_in[22];
  const float* s_w2   = (const float*)d_in[23];
  const float* s_b2   = (const float*)d_in[24];
  const float* s_wo   = (const float*)d_in[25];
  const float* s_bo   = (const float*)d_in[26];

  unsigned int* featws = (unsigned int*)d_ws;                  // 48*N*4 = 50,331,648 B
  unsigned short* w0b = (unsigned short*)(featws + 48u * NPTS);
  unsigned short* w1b = w0b + 8192;
  unsigned short* w2b = w1b + 65536;
  unsigned short* wob = w2b + 65536;
  unsigned int* ctr = (unsigned int*)(wob + 8192);             // 32 B, 16-aligned
  unsigned int* tb16 = ctr + 8;                                // 100,663,296 B
  size_t need_bt = ((char*)tb16 - (char*)d_ws) + (size_t)48 * TTAB * 4;
  bool use_bt = ws_size >= need_bt;

  ResArr res;
  double kk = (log(2048.0) - log(16.0)) / 15.0;
  for (int l = 0; l < 16; ++l) res.r[l] = (float)floor(16.0 * exp((double)l * kk));

  float* out = (float*)d_out;

  hipLaunchKernelGGL(cvt_kernel, dim3(256), dim3(256), 0, stream,
                     s_w0, s_w1, s_w2, s_wo, w0b, w1b, w2b, wob, ctr);
  if (use_bt) {
    hipLaunchKernelGGL(cvt_tab, dim3(24576), dim3(256), 0, stream,
                       t_sdf, t_color, t_sem, tb16);
    hipLaunchKernelGGL(hash_kernel<true>, dim3(HASH_BLOCKS), dim3(256), 0, stream,
                       p, bound, t_sdf, t_color, t_sem, tb16, featws, ctr, res);
  } else {
    hipLaunchKernelGGL(hash_kernel<false>, dim3(HASH_BLOCKS), dim3(256), 0, stream,
                       p, bound, t_sdf, t_color, t_sem, tb16, featws, ctr, res);
  }
  hipLaunchKernelGGL(mlp_small_kernel, dim3(1024), dim3(256), 0, stream,
                     featws, f_w0, f_b0, f_w1, f_b1, f_w2, f_b2, f_w3, f_b3,
                     osdf_w, osdf_b, orgb_w0, orgb_b0, orgb_w1, orgb_b1, out);
  hipLaunchKernelGGL(sem_kernel, dim3(NPTS / 64), dim3(512), 0, stream,
                     featws, w0b, w1b, w2b, wob, s_b0, s_b1, s_b2, s_bo, out);
}

// Round 4
// 588.134 us; speedup vs baseline: 2.0308x; 1.4501x over previous
//
#include <hip/hip_runtime.h>
#include <math.h>

#define NPTS 262144
#define TTAB 524288
#define TMASK (TTAB - 1)
#define PR1 2654435761u
#define PR2 805459861u

// merged-table hash: 16 levels x 256 chunks, 2 levels per XCD queue
#define MQ_SLOTS 512
#define MHASH_BLOCKS (8 * MQ_SLOTS)
// fp32 fallback path (ws too small): 48 pairs x 256 chunks
#define FQ_SLOTS 1536
#define FHASH_BLOCKS (8 * FQ_SLOTS)

typedef __attribute__((ext_vector_type(4))) float f32x4;
typedef __attribute__((ext_vector_type(8))) short bf16x8;
typedef __attribute__((ext_vector_type(3))) unsigned int uintx3;

struct ResArr { float r[16]; };

__device__ __forceinline__ float bf2f(unsigned int u) {
  union { unsigned int i; float f; } v; v.i = u << 16; return v.f;
}
__device__ __forceinline__ unsigned short f2bf(float f) {
  union { float f; unsigned int i; } v; v.f = f;
  unsigned int r = v.i + 0x7FFFu + ((v.i >> 16) & 1u);
  return (unsigned short)(r >> 16);
}
__device__ __forceinline__ unsigned int pack2(float a, float b) {
  return (unsigned int)f2bf(a) | ((unsigned int)f2bf(b) << 16);
}

// ---------------------------------------------------------------------------
// Tables fp32 -> merged packed-bf16: mt[(l*TTAB+idx)*3 + {sdf,color,sem}]
// One 12B entry holds all 3 tables' features for (level, idx).
// ---------------------------------------------------------------------------
__global__ __launch_bounds__(256) void cvt_tab(
    const float* __restrict__ t0, const float* __restrict__ t1,
    const float* __restrict__ t2, unsigned int* __restrict__ mt)
{
  size_t i = (size_t)blockIdx.x * 256 + threadIdx.x;   // l*TTAB + idx
  float2 a = ((const float2*)t0)[i];
  float2 b = ((const float2*)t1)[i];
  float2 c = ((const float2*)t2)[i];
  mt[i * 3 + 0] = pack2(a.x, a.y);
  mt[i * 3 + 1] = pack2(b.x, b.y);
  mt[i * 3 + 2] = pack2(c.x, c.y);
}

// ---------------------------------------------------------------------------
// Merged hash gather: one level per block-claim, XCD-affine queues.
// 8 x 12B dwordx3 gathers per point serve all 3 tables (3x fewer L2
// requests than per-table gathers). Level-major packed-bf16 features out.
// ---------------------------------------------------------------------------
__global__ __launch_bounds__(256) void hash_merged(
    const float* __restrict__ p, const float* __restrict__ bound,
    const unsigned int* __restrict__ mt,
    unsigned int* __restrict__ featws, unsigned int* __restrict__ ctr,
    ResArr res)
{
  __shared__ int s_slot;
  if (threadIdx.x == 0) {
    unsigned int xcc;
    asm volatile("s_getreg_b32 %0, hwreg(HW_REG_XCC_ID)" : "=s"(xcc));
    xcc &= 7u;
    int slot = -1;
    for (int k = 0; k < 8; ++k) {
      unsigned int q = (xcc + (unsigned int)k) & 7u;
      unsigned int s = atomicAdd(ctr + q, 1u);
      if (s < MQ_SLOTS) { slot = (int)(q * MQ_SLOTS + s); break; }
    }
    s_slot = slot;
  }
  __syncthreads();
  int slot = s_slot;
  if (slot < 0) return;

  unsigned int q = (unsigned int)slot / MQ_SLOTS;
  unsigned int s = (unsigned int)slot - q * MQ_SLOTS;
  unsigned int level = (s >> 8) * 8u + q;        // 0..15, queue q gets {q, q+8}
  unsigned int chunk = s & 255u;

  float r = res.r[0];
#pragma unroll
  for (int l = 1; l < 16; ++l) r = (level == (unsigned int)l) ? res.r[l] : r;

  float b0 = bound[0], b1 = bound[1], b2 = bound[2], b3 = bound[3],
        b4 = bound[4], b5 = bound[5];
  float i0v = 1.f / (b1 - b0), i1v = 1.f / (b3 - b2), i2v = 1.f / (b5 - b4);
  const unsigned int* mtl = mt + (size_t)level * TTAB * 3u;
  unsigned int f0 = (0u * 16u + level) * (unsigned int)NPTS;
  unsigned int f1 = (1u * 16u + level) * (unsigned int)NPTS;
  unsigned int f2b = (2u * 16u + level) * (unsigned int)NPTS;
  unsigned int nbase = chunk * 1024u + threadIdx.x;

#pragma unroll
  for (int half = 0; half < 2; ++half) {
    unsigned int CX[2], CY[2], CZ[2];
    float DX[2], DY[2], DZ[2];
#pragma unroll
    for (int pt = 0; pt < 2; ++pt) {
      unsigned int n = nbase + (unsigned int)(half * 512 + pt * 256);
      float px = p[n * 3 + 0], py = p[n * 3 + 1], pz = p[n * 3 + 2];
      float sx = (px - b0) * i0v * r;
      float sy = (py - b2) * i1v * r;
      float sz = (pz - b4) * i2v * r;
      float fx = floorf(sx), fy = floorf(sy), fz = floorf(sz);
      DX[pt] = sx - fx; DY[pt] = sy - fy; DZ[pt] = sz - fz;
      CX[pt] = (unsigned int)fx;
      CY[pt] = (unsigned int)fy * PR1;
      CZ[pt] = (unsigned int)fz * PR2;
    }
    __builtin_amdgcn_sched_barrier(0);

    uintx3 V[2][8];
#pragma unroll
    for (int pt = 0; pt < 2; ++pt) {
      unsigned int x0 = CX[pt], x1 = CX[pt] + 1u;
      unsigned int y0 = CY[pt], y1 = y0 + PR1;
      unsigned int z0 = CZ[pt], z1 = z0 + PR2;
      unsigned int id[8];
      id[0] = (x0 ^ y0 ^ z0) & TMASK;
      id[1] = (x0 ^ y0 ^ z1) & TMASK;
      id[2] = (x0 ^ y1 ^ z0) & TMASK;
      id[3] = (x0 ^ y1 ^ z1) & TMASK;
      id[4] = (x1 ^ y0 ^ z0) & TMASK;
      id[5] = (x1 ^ y0 ^ z1) & TMASK;
      id[6] = (x1 ^ y1 ^ z0) & TMASK;
      id[7] = (x1 ^ y1 ^ z1) & TMASK;
#pragma unroll
      for (int c = 0; c < 8; ++c)
        V[pt][c] = *(const uintx3*)(mtl + (size_t)id[c] * 3u);
    }
    __builtin_amdgcn_sched_barrier(0);

#pragma unroll
    for (int pt = 0; pt < 2; ++pt) {
      float dx = DX[pt], dy = DY[pt], dz = DZ[pt];
      float wx[2] = { 1.f - dx, dx }, wy[2] = { 1.f - dy, dy }, wz[2] = { 1.f - dz, dz };
      float a00 = 0.f, a01 = 0.f, a10 = 0.f, a11 = 0.f, a20 = 0.f, a21 = 0.f;
#pragma unroll
      for (int c = 0; c < 8; ++c) {
        float w = wx[c >> 2] * wy[(c >> 1) & 1] * wz[c & 1];
        unsigned int u0 = V[pt][c].x, u1 = V[pt][c].y, u2 = V[pt][c].z;
        a00 += bf2f(u0 << 16) * w;  a01 += bf2f(u0 & 0xFFFF0000u) * w;
        a10 += bf2f(u1 << 16) * w;  a11 += bf2f(u1 & 0xFFFF0000u) * w;
        a20 += bf2f(u2 << 16) * w;  a21 += bf2f(u2 & 0xFFFF0000u) * w;
      }
      unsigned int n = nbase + (unsigned int)(half * 512 + pt * 256);
      featws[f0 + n] = pack2(a00, a01);
      featws[f1 + n] = pack2(a10, a11);
      featws[f2b + n] = pack2(a20, a21);
    }
  }
}

// ---------------------------------------------------------------------------
// fp32 fallback (only if ws too small for merged tables): per-(table,level)
// ---------------------------------------------------------------------------
__global__ __launch_bounds__(256) void hash_f32(
    const float* __restrict__ p, const float* __restrict__ bound,
    const float* __restrict__ t0, const float* __restrict__ t1,
    const float* __restrict__ t2,
    unsigned int* __restrict__ featws, unsigned int* __restrict__ ctr,
    ResArr res)
{
  __shared__ int s_pad[10240];
  if (threadIdx.x == 0) {
    unsigned int xcc;
    asm volatile("s_getreg_b32 %0, hwreg(HW_REG_XCC_ID)" : "=s"(xcc));
    xcc &= 7u;
    int slot = -1;
    for (int k = 0; k < 8; ++k) {
      unsigned int q = (xcc + (unsigned int)k) & 7u;
      unsigned int s = atomicAdd(ctr + q, 1u);
      if (s < FQ_SLOTS) { slot = (int)(q * FQ_SLOTS + s); break; }
    }
    s_pad[0] = slot;
  }
  __syncthreads();
  int slot = s_pad[0];
  if (slot < 0) return;

  unsigned int q = (unsigned int)slot / FQ_SLOTS;
  unsigned int s = (unsigned int)slot - q * FQ_SLOTS;
  unsigned int i = (s >> 8) * 8u + q;
  unsigned int level = i / 3u;
  unsigned int table = i - level * 3u;
  unsigned int chunk = s & 255u;

  float r = res.r[0];
#pragma unroll
  for (int l = 1; l < 16; ++l) r = (level == (unsigned int)l) ? res.r[l] : r;

  float b0 = bound[0], b1 = bound[1], b2 = bound[2], b3 = bound[3],
        b4 = bound[4], b5 = bound[5];
  const float* tf = ((table == 0u) ? t0 : (table == 1u) ? t1 : t2) +
                    (size_t)level * (TTAB * 2);
  unsigned int fbase = (table * 16u + level) * (unsigned int)NPTS;
  unsigned int nbase = chunk * 1024u + threadIdx.x;

#pragma unroll
  for (int it = 0; it < 4; ++it) {
    unsigned int n = nbase + (unsigned int)it * 256u;
    float px = p[n * 3 + 0], py = p[n * 3 + 1], pz = p[n * 3 + 2];
    float x = (px - b0) / (b1 - b0);
    float y = (py - b2) / (b3 - b2);
    float z = (pz - b4) / (b5 - b4);
    float sx = x * r, sy = y * r, sz = z * r;
    float fx = floorf(sx), fy = floorf(sy), fz = floorf(sz);
    float dx = sx - fx, dy = sy - fy, dz = sz - fz;
    unsigned int cx = (unsigned int)fx, cy = (unsigned int)fy, cz = (unsigned int)fz;
    unsigned int hx[2] = { cx, cx + 1u };
    unsigned int hy[2] = { cy * PR1, (cy + 1u) * PR1 };
    unsigned int hz[2] = { cz * PR2, (cz + 1u) * PR2 };
    float wx[2] = { 1.f - dx, dx }, wy[2] = { 1.f - dy, dy }, wz[2] = { 1.f - dz, dz };
    float a0 = 0.f, a1 = 0.f;
#pragma unroll
    for (int ii = 0; ii < 2; ++ii)
#pragma unroll
      for (int jj = 0; jj < 2; ++jj)
#pragma unroll
        for (int kk = 0; kk < 2; ++kk) {
          unsigned int idx = (hx[ii] ^ hy[jj] ^ hz[kk]) & TMASK;
          float2 f2 = *(const float2*)(tf + (size_t)idx * 2);
          float w = wx[ii] * wy[jj] * wz[kk];
          a0 += f2.x * w;
          a1 += f2.y * w;
        }
    featws[fbase + n] = pack2(a0, a1);
  }
}

// ---------------------------------------------------------------------------
// Small MLPs (sdf chain + rgb) + plane_feat writeout. One thread per point.
// ---------------------------------------------------------------------------
__global__ __launch_bounds__(256) void mlp_small_kernel(
    const unsigned int* __restrict__ fws,
    const float* __restrict__ fw0, const float* __restrict__ fb0,
    const float* __restrict__ fw1, const float* __restrict__ fb1,
    const float* __restrict__ fw2, const float* __restrict__ fb2,
    const float* __restrict__ fw3, const float* __restrict__ fb3,
    const float* __restrict__ ow, const float* __restrict__ ob,
    const float* __restrict__ rw0, const float* __restrict__ rb0,
    const float* __restrict__ rw1, const float* __restrict__ rb1,
    float* __restrict__ out)
{
  unsigned int n = blockIdx.x * 256 + threadIdx.x;
  float ft[32], cf[32], sf[32];
#pragma unroll
  for (int l = 0; l < 16; ++l) {
    unsigned int u = fws[(0u * 16 + l) * (unsigned int)NPTS + n];
    ft[2 * l] = bf2f(u << 16); ft[2 * l + 1] = bf2f(u & 0xFFFF0000u);
    u = fws[(1u * 16 + l) * (unsigned int)NPTS + n];
    cf[2 * l] = bf2f(u << 16); cf[2 * l + 1] = bf2f(u & 0xFFFF0000u);
    u = fws[(2u * 16 + l) * (unsigned int)NPTS + n];
    sf[2 * l] = bf2f(u << 16); sf[2 * l + 1] = bf2f(u & 0xFFFF0000u);
  }

  // plane_feat = [c_feat[16:], f_feat[16:], s_feat[16:]] fp32
  {
    float* pf = out + (size_t)NPTS * 29 + (size_t)n * 48;
#pragma unroll
    for (int i2 = 0; i2 < 16; i2 += 4)
      *(float4*)(pf + i2) = make_float4(cf[16 + i2], cf[17 + i2], cf[18 + i2], cf[19 + i2]);
#pragma unroll
    for (int i2 = 0; i2 < 16; i2 += 4)
      *(float4*)(pf + 16 + i2) = make_float4(ft[16 + i2], ft[17 + i2], ft[18 + i2], ft[19 + i2]);
#pragma unroll
    for (int i2 = 0; i2 < 16; i2 += 4)
      *(float4*)(pf + 32 + i2) = make_float4(sf[16 + i2], sf[17 + i2], sf[18 + i2], sf[19 + i2]);
  }

  float h[16], g[16];
  for (int o = 0; o < 16; ++o) {
    float a = fb0[o];
    for (int i2 = 0; i2 < 32; ++i2) a += ft[i2] * fw0[o * 32 + i2];
    h[o] = fmaxf(a, 0.f);
  }
  for (int o = 0; o < 16; ++o) {
    float a = fb1[o];
    for (int i2 = 0; i2 < 16; ++i2) a += h[i2] * fw1[o * 16 + i2];
    g[o] = fmaxf(a, 0.f);
  }
  for (int o = 0; o < 16; ++o) {
    float a = fb2[o];
    for (int i2 = 0; i2 < 16; ++i2) a += g[i2] * fw2[o * 16 + i2];
    h[o] = fmaxf(a, 0.f);
  }
  for (int o = 0; o < 16; ++o) {
    float a = fb3[o];
    for (int i2 = 0; i2 < 16; ++i2) a += h[i2] * fw3[o * 16 + i2];
    g[o] = fmaxf(a, 0.f);
  }
  float so[17];
  for (int o = 0; o < 17; ++o) {
    float a = ob[o];
    for (int i2 = 0; i2 < 16; ++i2) a += g[i2] * ow[o * 16 + i2];
    so[o] = a;
  }
  float sdf = tanhf(so[0]);
  float rin[80];
#pragma unroll
  for (int i2 = 0; i2 < 16; ++i2) rin[i2] = so[i2 + 1];
#pragma unroll
  for (int i2 = 0; i2 < 32; ++i2) rin[16 + i2] = cf[i2];
#pragma unroll
  for (int i2 = 0; i2 < 32; ++i2) rin[48 + i2] = sf[i2];
  float hr[16];
  for (int o = 0; o < 16; ++o) {
    float a = rb0[o];
    for (int i2 = 0; i2 < 80; ++i2) a += rin[i2] * rw0[o * 80 + i2];
    hr[o] = fmaxf(a, 0.f);
  }
  float* po = out + (size_t)n * 29;
  for (int o = 0; o < 3; ++o) {
    float a = rb1[o];
    for (int i2 = 0; i2 < 16; ++i2) a += hr[i2] * rw1[o * 16 + i2];
    po[o] = 1.f / (1.f + expf(-a));
  }
  po[3] = sdf;
}

// ---------------------------------------------------------------------------
// Weight fp32 -> bf16 (semantic MLP; wo zero-padded 25->32 rows) + ctr zero.
// ---------------------------------------------------------------------------
__global__ __launch_bounds__(256) void cvt_kernel(
    const float* __restrict__ sw0, const float* __restrict__ sw1,
    const float* __restrict__ sw2, const float* __restrict__ swo,
    unsigned short* __restrict__ w0, unsigned short* __restrict__ w1,
    unsigned short* __restrict__ w2, unsigned short* __restrict__ wo,
    unsigned int* __restrict__ ctr)
{
  int t = blockIdx.x * 256 + threadIdx.x;   // grid covers 65536
  if (t < 8) ctr[t] = 0u;
  if (t < 8192) w0[t] = f2bf(sw0[t]);
  w1[t] = f2bf(sw1[t]);
  w2[t] = f2bf(sw2[t]);
  if (t < 8192) wo[t] = (t < 6400) ? f2bf(swo[t]) : (unsigned short)0;
}

// ---------------------------------------------------------------------------
// Semantic MLP 32->256->256->256->25 via bf16 MFMA 16x16x32.
// 256 threads / 4 waves, M=64, 64 cols per wave (acc[4][4]); a-frags shared
// across 4 col-tiles (0.5 loads/MFMA); weight frags double-buffered so
// global loads sit outside the MFMA dependency chain.
// ---------------------------------------------------------------------------
#define LAYER256(Hin, Wp, Bp, Hout)                                                        \
  {                                                                                        \
    _Pragma("unroll") for (int r = 0; r < 4; ++r)                                          \
      _Pragma("unroll") for (int c = 0; c < 4; ++c)                                        \
        acc[r][c] = (f32x4){0.f, 0.f, 0.f, 0.f};                                           \
    _Pragma("unroll") for (int c = 0; c < 4; ++c)                                          \
      bc[c] = *(const bf16x8*)(Wp + (size_t)(cw + c * 16 + l16) * 256 + quad * 8);         \
    _Pragma("unroll") for (int ks = 0; ks < 8; ++ks) {                                     \
      int k0 = ks * 32;                                                                    \
      if (ks < 7) {                                                                        \
        _Pragma("unroll") for (int c = 0; c < 4; ++c)                                      \
          bn[c] = *(const bf16x8*)(Wp + (size_t)(cw + c * 16 + l16) * 256 + k0 + 32 + quad * 8); \
      }                                                                                    \
      _Pragma("unroll") for (int r = 0; r < 4; ++r)                                        \
        a[r] = *(const bf16x8*)(Hin + (r * 16 + l16) * 264 + k0 + quad * 8);               \
      _Pragma("unroll") for (int r = 0; r < 4; ++r)                                        \
        _Pragma("unroll") for (int c = 0; c < 4; ++c)                                      \
          acc[r][c] = __builtin_amdgcn_mfma_f32_16x16x32_bf16(a[r], bc[c], acc[r][c], 0, 0, 0); \
      _Pragma("unroll") for (int c = 0; c < 4; ++c) bc[c] = bn[c];                         \
    }                                                                                      \
    _Pragma("unroll") for (int c = 0; c < 4; ++c) {                                        \
      int col = cw + c * 16 + l16;                                                         \
      float bias = Bp[col];                                                                \
      _Pragma("unroll") for (int r = 0; r < 4; ++r)                                        \
        _Pragma("unroll") for (int g2 = 0; g2 < 4; ++g2) {                                 \
          int row = r * 16 + quad * 4 + g2;                                                \
          Hout[row * 264 + col] = f2bf(fmaxf(acc[r][c][g2] + bias, 0.f));                  \
        }                                                                                  \
    }                                                                                      \
    __syncthreads();                                                                       \
  }

__global__ __launch_bounds__(256) void sem_kernel(
    const unsigned int* __restrict__ fws,
    const unsigned short* __restrict__ w0, const unsigned short* __restrict__ w1,
    const unsigned short* __restrict__ w2, const unsigned short* __restrict__ wo,
    const float* __restrict__ b0, const float* __restrict__ b1,
    const float* __restrict__ b2, const float* __restrict__ bo,
    float* __restrict__ out)
{
  __shared__ alignas(16) unsigned short X[64 * 40];
  __shared__ alignas(16) unsigned short HA[64 * 264];
  __shared__ alignas(16) unsigned short HB[64 * 264];

  int tid = threadIdx.x;
  int n0 = blockIdx.x * 64;
  int lane = tid & 63, wv = tid >> 6;       // 4 waves
  int l16 = lane & 15, quad = lane >> 4;
  int cw = wv * 64;

  // stage X: 64 rows x 16 level-dwords
#pragma unroll
  for (int h = 0; h < 4; ++h) {
    int idx = tid + h * 256;
    int row = idx & 63;
    int l = idx >> 6;
    unsigned int v = fws[(32u + (unsigned int)l) * (unsigned int)NPTS + (unsigned int)(n0 + row)];
    *(unsigned int*)(X + row * 40 + 2 * l) = v;
  }
  __syncthreads();

  f32x4 acc[4][4];
  bf16x8 a[4], bc[4], bn[4];

  // ---- layer 0 (K=32): X @ W0^T -> HA ----
#pragma unroll
  for (int r = 0; r < 4; ++r)
#pragma unroll
    for (int c = 0; c < 4; ++c) acc[r][c] = (f32x4){0.f, 0.f, 0.f, 0.f};
#pragma unroll
  for (int r = 0; r < 4; ++r) a[r] = *(const bf16x8*)(X + (r * 16 + l16) * 40 + quad * 8);
#pragma unroll
  for (int c = 0; c < 4; ++c) bc[c] = *(const bf16x8*)(w0 + (size_t)(cw + c * 16 + l16) * 32 + quad * 8);
#pragma unroll
  for (int r = 0; r < 4; ++r)
#pragma unroll
    for (int c = 0; c < 4; ++c)
      acc[r][c] = __builtin_amdgcn_mfma_f32_16x16x32_bf16(a[r], bc[c], acc[r][c], 0, 0, 0);
#pragma unroll
  for (int c = 0; c < 4; ++c) {
    int col = cw + c * 16 + l16;
    float bias = b0[col];
#pragma unroll
    for (int r = 0; r < 4; ++r)
#pragma unroll
      for (int g2 = 0; g2 < 4; ++g2) {
        int row = r * 16 + quad * 4 + g2;
        HA[row * 264 + col] = f2bf(fmaxf(acc[r][c][g2] + bias, 0.f));
      }
  }
  __syncthreads();

  // ---- layer 1: HA @ W1^T -> HB ----
  LAYER256(HA, w1, b1, HB)
  // ---- layer 2: HB @ W2^T -> HA ----
  LAYER256(HB, w2, b2, HA)

  // ---- output layer (25 cols): HA @ Wo^T -> d_out ----
  // wave wv handles rows [wv*16, wv*16+16), cols 0..31
  {
    f32x4 acc2[2];
    acc2[0] = (f32x4){0.f, 0.f, 0.f, 0.f};
    acc2[1] = (f32x4){0.f, 0.f, 0.f, 0.f};
#pragma unroll
    for (int ks = 0; ks < 8; ++ks) {
      int k0 = ks * 32;
      bf16x8 af = *(const bf16x8*)(HA + (wv * 16 + l16) * 264 + k0 + quad * 8);
#pragma unroll
      for (int c = 0; c < 2; ++c) {
        bf16x8 bf = *(const bf16x8*)(wo + (size_t)(c * 16 + l16) * 256 + k0 + quad * 8);
        acc2[c] = __builtin_amdgcn_mfma_f32_16x16x32_bf16(af, bf, acc2[c], 0, 0, 0);
      }
    }
#pragma unroll
    for (int c = 0; c < 2; ++c) {
      int col = c * 16 + l16;
      if (col < 25) {
        float bias = bo[col];
#pragma unroll
        for (int g2 = 0; g2 < 4; ++g2) {
          int row = wv * 16 + quad * 4 + g2;
          out[(size_t)(n0 + row) * 29 + 4 + col] = acc2[c][g2] + bias;
        }
      }
    }
  }
}

// ---------------------------------------------------------------------------
extern "C" void kernel_launch(void* const* d_in, const int* in_sizes, int n_in,
                              void* d_out, int out_size, void* d_ws, size_t ws_size,
                              hipStream_t stream) {
  const float* p      = (const float*)d_in[0];
  const float* bound  = (const float*)d_in[1];
  const float* t_sdf  = (const float*)d_in[2];
  const float* t_color= (const float*)d_in[3];
  const float* t_sem  = (const float*)d_in[4];
  const float* f_w0   = (const float*)d_in[5];
  const float* f_b0   = (const float*)d_in[6];
  const float* f_w1   = (const float*)d_in[7];
  const float* f_b1   = (const float*)d_in[8];
  const float* f_w2   = (const float*)d_in[9];
  const float* f_b2   = (const float*)d_in[10];
  const float* f_w3   = (const float*)d_in[11];
  const float* f_b3   = (const float*)d_in[12];
  const float* osdf_w = (const float*)d_in[13];
  const float* osdf_b = (const float*)d_in[14];
  const float* orgb_w0= (const float*)d_in[15];
  const float* orgb_b0= (const float*)d_in[16];
  const float* orgb_w1= (const float*)d_in[17];
  const float* orgb_b1= (const float*)d_in[18];
  const float* s_w0   = (const float*)d_in[19];
  const float* s_b0   = (const float*)d_in[20];
  const float* s_w1   = (const float*)d_in[21];
  const float* s_b1   = (const float*)d_in[22];
  const float* s_w2   = (const float*)d_in[23];
  const float* s_b2   = (const float*)d_in[24];
  const float* s_wo   = (const float*)d_in[25];
  const float* s_bo   = (const float*)d_in[26];

  unsigned int* featws = (unsigned int*)d_ws;                  // 48*N*4 = 50,331,648 B
  unsigned short* w0b = (unsigned short*)(featws + 48u * NPTS);
  unsigned short* w1b = w0b + 8192;
  unsigned short* w2b = w1b + 65536;
  unsigned short* wob = w2b + 65536;
  unsigned int* ctr = (unsigned int*)(wob + 8192);             // 32 B, 16-aligned
  unsigned int* mt = ctr + 8;                                  // 100,663,296 B
  size_t need_bt = ((char*)mt - (char*)d_ws) + (size_t)16 * TTAB * 12;
  bool use_bt = ws_size >= need_bt;

  ResArr res;
  double kk = (log(2048.0) - log(16.0)) / 15.0;
  for (int l = 0; l < 16; ++l) res.r[l] = (float)floor(16.0 * exp((double)l * kk));

  float* out = (float*)d_out;

  hipLaunchKernelGGL(cvt_kernel, dim3(256), dim3(256), 0, stream,
                     s_w0, s_w1, s_w2, s_wo, w0b, w1b, w2b, wob, ctr);
  if (use_bt) {
    hipLaunchKernelGGL(cvt_tab, dim3(32768), dim3(256), 0, stream,
                       t_sdf, t_color, t_sem, mt);
    hipLaunchKernelGGL(hash_merged, dim3(MHASH_BLOCKS), dim3(256), 0, stream,
                       p, bound, mt, featws, ctr, res);
  } else {
    hipLaunchKernelGGL(hash_f32, dim3(FHASH_BLOCKS), dim3(256), 0, stream,
                       p, bound, t_sdf, t_color, t_sem, featws, ctr, res);
  }
  hipLaunchKernelGGL(mlp_small_kernel, dim3(1024), dim3(256), 0, stream,
                     featws, f_w0, f_b0, f_w1, f_b1, f_w2, f_b2, f_w3, f_b3,
                     osdf_w, osdf_b, orgb_w0, orgb_b0, orgb_w1, orgb_b1, out);
  hipLaunchKernelGGL(sem_kernel, dim3(NPTS / 64), dim3(256), 0, stream,
                     featws, w0b, w1b, w2b, wob, s_b0, s_b1, s_b2, s_bo, out);
}